// Round 27
// baseline (149.249 us; speedup 1.0000x reference)
//
#include <hip/hip_runtime.h>

// VQ-VAE VectorQuantizer fwd. K=1024, E=64, N=T*B=65536.
// 2-tier argmin: 3-term bf16-split MFMA (GAP1=6e-6) -> fp64 exact.
// R27: FETCH forensics showed nf (flagged rows) ~5-6K, not ~250 -- R25/R26's
// exact64 was 11 rows/wave serial at 0.5 block/CU (Occ 1.7%). Fix: exact64
// grid 128 -> 1024 blocks (1-2 rows/wave) + fp64 accum split into paired
// chains (s0/s1, e0/e1) to halve serial latency. Nothing else changed.
// Scores t = ||c||^2 - 2 x.c; codebook pre-scaled by -2, ||c||^2 in C-init.
// MFMA: A = codebook frag, B = x frag -> D(lane l, reg r) =
// score(code = t*16 + (l>>4)*4 + r, row = base + (l&15)).

#define KC 1024
#define ED 64
#define NR 65536
#define NE (NR * ED)
#define GAP1 6e-6f

typedef __attribute__((ext_vector_type(8))) short short8;
typedef __attribute__((ext_vector_type(4))) float f32x4;

__device__ __forceinline__ unsigned short bf16rne(float f) {
    unsigned u = __builtin_bit_cast(unsigned, f);
    return (unsigned short)((u + 0x7fffu + ((u >> 16) & 1u)) >> 16);
}
__device__ __forceinline__ float bf16tof(unsigned short h) {
    return __builtin_bit_cast(float, (unsigned)h << 16);
}

// Pack compact tile records (stride 320 short8 = 5KB) + cbT4 (float4
// transposed codebook: cbT4[e4*KC + k] = cb[k][e4*4..e4*4+3]) + zero ctrs.
// Record t: j=0,1 = ch (hi bf16 of -2*c) for e in [0,32),[32,64); j=2,3 =
// cl (lo residual); elem (g=l>>4,r) <-> e = (j&1)*32 + g*8 + r (same
// bijection as the x fragments); j=4: f32x4 ||c||^2 (reg r <-> code
// t*16+(l>>4)*4+r) bitcast short8.
__global__ __launch_bounds__(256) void k_pack(const float* __restrict__ cb,
        short8* __restrict__ cbt, float4* __restrict__ cbT4,
        unsigned* __restrict__ counts, unsigned* __restrict__ flagcnt,
        unsigned* __restrict__ done) {
    const int u = blockIdx.x * 256 + threadIdx.x;
    if (u < 1024) counts[u] = 0u;
    if (u == 1024) *flagcnt = 0u;
    if (u == 1025) *done = 0u;
    if (u < 16384) {                              // cbT4: u = e4*KC + k
        const int e4 = u >> 10, k = u & 1023;
        cbT4[u] = ((const float4*)(cb + (size_t)k * ED))[e4];
    }
    if (u >= 64 * 5 * 64) return;
    const int t = u / 320, rem = u % 320, j = rem / 64, l = rem % 64;
    const int g = l >> 4;
    if (j < 4) {
        const int code = t * 16 + (l & 15);
        const float* c = cb + (size_t)code * ED;
        const bool lo = (j >= 2);
        short8 o;
#pragma unroll
        for (int r = 0; r < 8; ++r) {
            const int e = (j & 1) * 32 + g * 8 + r;
            const float m2 = -2.f * c[e];
            const unsigned short h = bf16rne(m2);
            o[r] = lo ? (short)bf16rne(m2 - bf16tof(h)) : (short)h;
        }
        cbt[u] = o;
    } else {
        f32x4 o;
#pragma unroll
        for (int r = 0; r < 4; ++r) {
            const float4* c4 = (const float4*)(cb + (size_t)(t * 16 + g * 4 + r) * ED);
            float s0 = 0.f, s1 = 0.f, s2 = 0.f, s3 = 0.f;
#pragma unroll
            for (int i = 0; i < 16; ++i) {
                const float4 c = c4[i];
                s0 = fmaf(c.x, c.x, s0); s1 = fmaf(c.y, c.y, s1);
                s2 = fmaf(c.z, c.z, s2); s3 = fmaf(c.w, c.w, s3);
            }
            o[r] = (s0 + s1) + (s2 + s3);
        }
        cbt[u] = __builtin_bit_cast(short8, o);
    }
}

// 2048 blocks x 256 thr (4 waves = 4 K-quarters), 32 rows/block, 8
// blocks/CU. Phase 1: cooperative x -> bf16 hi/lo frags into LDS +
// ||x||^2 partials. Phase 2: wave kh holds its 8 x-frags in 32 VGPR
// (resident), scans tiles [kh*16,+16): 5 loads + 12 MFMA + min-track.
// Phase 3: shfl g-merge; wave 0 (lanes<32) merges kh slices (ascending k
// tie-break), writes idx/fidx/histogram/flag/SSE. Phase 4: qout gather.
__global__ __launch_bounds__(256) void k_argmin(
        const float* __restrict__ in, const short8* __restrict__ cbt,
        const float* __restrict__ cb, int* __restrict__ idx,
        float* __restrict__ qout, unsigned* __restrict__ counts,
        unsigned* __restrict__ flagcnt, unsigned* __restrict__ flaglist,
        double* __restrict__ pblk) {
    __shared__ short8 xs[8][64];                  // 8 KB
    __shared__ float rx2p[8][32];                 // 1 KB
    __shared__ float sb[4][2][16], sb2[4][2][16];
    __shared__ int   sk[4][2][16];                // 1.5 KB
    __shared__ int   fidx[32];

    const int tid = threadIdx.x;
    const int l = tid & 63;
    const int wid = tid >> 6;                     // 0..3 == kh
    const int g = l >> 4;
    const int col = l & 15;
    const int rowBase = blockIdx.x * 32;

    // Phase 1: thread (row=tid&31, ob=tid>>5) converts its row's oct ob
    // (e = ob*8+j; hh=ob>>2, gg=ob&3); ll = gg*16+(row&15),
    // slot = (row>>4)*4 + hh (+2 for lo).
    {
        const int row = tid & 31;
        const int ob = tid >> 5;                  // 0..7
        const int hh = ob >> 2, gg = ob & 3;
        const int rt = row >> 4;
        const int ll = gg * 16 + (row & 15);
        float part = 0.f;
        short8 H, L;
#pragma unroll
        for (int j = 0; j < 8; ++j) {
            const float x = in[(size_t)(ob * 8 + j) * NR + rowBase + row];
            const unsigned short hb = bf16rne(x);
            H[j] = (short)hb;
            L[j] = (short)bf16rne(x - bf16tof(hb));
            part = fmaf(x, x, part);
        }
        xs[rt * 4 + hh][ll] = H;
        xs[rt * 4 + 2 + hh][ll] = L;
        rx2p[ob][row] = part;
    }
    __syncthreads();

    // Phase 2: 8 x-frags to regs (32 VGPR, resident), simple tile loop.
    const int kh = wid;
    short8 xq[2][4];
#pragma unroll
    for (int rt = 0; rt < 2; ++rt)
#pragma unroll
        for (int q = 0; q < 4; ++q)
            xq[rt][q] = xs[rt * 4 + q][l];

    float best[2]  = {3.4e38f, 3.4e38f};
    float best2[2] = {3.4e38f, 3.4e38f};
    int bestk[2] = {0, 0};

#pragma unroll 2
    for (int tt = 0; tt < 16; ++tt) {
        const int t = kh * 16 + tt;
        const short8* bp = cbt + (size_t)t * 320 + l;
        const short8 b0 = bp[0], b1 = bp[64], b2 = bp[128], b3 = bp[192];
        const f32x4 e4 = __builtin_bit_cast(f32x4, bp[256]);
#pragma unroll
        for (int rt = 0; rt < 2; ++rt) {
            f32x4 acc = e4;
            acc = __builtin_amdgcn_mfma_f32_16x16x32_bf16(b0, xq[rt][0], acc, 0, 0, 0);
            acc = __builtin_amdgcn_mfma_f32_16x16x32_bf16(b1, xq[rt][1], acc, 0, 0, 0);
            acc = __builtin_amdgcn_mfma_f32_16x16x32_bf16(b2, xq[rt][0], acc, 0, 0, 0);
            acc = __builtin_amdgcn_mfma_f32_16x16x32_bf16(b3, xq[rt][1], acc, 0, 0, 0);
            acc = __builtin_amdgcn_mfma_f32_16x16x32_bf16(b0, xq[rt][2], acc, 0, 0, 0);
            acc = __builtin_amdgcn_mfma_f32_16x16x32_bf16(b1, xq[rt][3], acc, 0, 0, 0);
#pragma unroll
            for (int r = 0; r < 4; ++r) {
                const float v = acc[r];
                const int k = t * 16 + g * 4 + r;
                best2[rt] = fminf(fmaxf(v, best[rt]), best2[rt]);  // med3
                const bool c = v < best[rt];
                bestk[rt] = c ? k : bestk[rt];
                best[rt]  = fminf(v, best[rt]);
            }
        }
    }

    // Phase 3a: intra-wave g-merge; g==0 writes per-kh partials.
#pragma unroll
    for (int rt = 0; rt < 2; ++rt) {
        float b = best[rt], b2 = best2[rt]; int k = bestk[rt];
#pragma unroll
        for (int sh = 16; sh <= 32; sh <<= 1) {
            const float ob  = __shfl_xor(b, sh, 64);
            const float ob2 = __shfl_xor(b2, sh, 64);
            const int   ok  = __shfl_xor(k, sh, 64);
            if (ob < b || (ob == b && ok < k)) { b2 = fminf(b, ob2); k = ok; b = ob; }
            else b2 = fminf(b2, ob);
        }
        if (g == 0) { sb[wid][rt][col] = b; sb2[wid][rt][col] = b2; sk[wid][rt][col] = k; }
    }
    __syncthreads();

    // Phase 3b: wave 0, lanes < 32: lane l owns row ((l>>4)&1)*16 + (l&15).
    if (wid == 0) {
        const int rt = (l >> 4) & 1, c2 = l & 15;
        const bool act = (l < 32);
        float b = sb[0][rt][c2], b2 = sb2[0][rt][c2]; int k = sk[0][rt][c2];
#pragma unroll
        for (int s = 1; s < 4; ++s) {              // ascending k ranges
            const float ob = sb[s][rt][c2], ob2 = sb2[s][rt][c2];
            const int ok = sk[s][rt][c2];
            if (ob < b || (ob == b && ok < k)) { b2 = fminf(b, ob2); k = ok; b = ob; }
            else b2 = fminf(b2, ob);
        }
        const int lrow = rt * 16 + c2;
        const int row = rowBase + lrow;
        double d2 = 0.0;
        if (act) {
            idx[row] = k;
            fidx[lrow] = k;
            atomicAdd(&counts[k], 1u);
            if (b2 - b < GAP1) {
                const unsigned p = atomicAdd(flagcnt, 1u);
                flaglist[p] = (unsigned)row;
            }
            float rx = 0.f;
#pragma unroll
            for (int o = 0; o < 8; ++o) rx += rx2p[o][lrow];
            d2 = (double)b + (double)rx;
        }
#pragma unroll
        for (int off = 16; off > 0; off >>= 1) d2 += __shfl_down(d2, off, 64);
        if (l == 0) pblk[blockIdx.x] = d2;
    }
    __syncthreads();

    // Phase 4: cooperative gather; thread (row=tid&31, e0=tid>>5).
    {
        const int row = tid & 31;
        const int e0 = tid >> 5;                  // 0..7
        const int k = fidx[row];
        const float4* c4 = (const float4*)(cb + (size_t)k * ED + e0 * 8);
        const float4 v0 = c4[0], v1 = c4[1];
        qout[(size_t)(e0 * 8 + 0) * NR + rowBase + row] = v0.x;
        qout[(size_t)(e0 * 8 + 1) * NR + rowBase + row] = v0.y;
        qout[(size_t)(e0 * 8 + 2) * NR + rowBase + row] = v0.z;
        qout[(size_t)(e0 * 8 + 3) * NR + rowBase + row] = v0.w;
        qout[(size_t)(e0 * 8 + 4) * NR + rowBase + row] = v1.x;
        qout[(size_t)(e0 * 8 + 5) * NR + rowBase + row] = v1.y;
        qout[(size_t)(e0 * 8 + 6) * NR + rowBase + row] = v1.z;
        qout[(size_t)(e0 * 8 + 7) * NR + rowBase + row] = v1.w;
    }
}

// fp64 exact argmin for flagged rows (~5-6K) + FUSED final scalars.
// 1024 blocks (4096 waves -> 1-2 rows/wave). Coalesced cbT4 loads; paired
// fp64 chains (s0/s1, e0/e1). Fixes idx/counts/qout on change.
__global__ __launch_bounds__(256) void k_exact64(
        const float* __restrict__ in, const float* __restrict__ cb,
        const float4* __restrict__ cbT4, int* __restrict__ idx,
        float* __restrict__ qout, unsigned* __restrict__ counts,
        const unsigned* __restrict__ flagcnt, const unsigned* __restrict__ flaglist,
        unsigned* __restrict__ done, const double* __restrict__ pblk,
        float* __restrict__ out) {
    __shared__ float4 xls4[4][16];
    const unsigned nf = *flagcnt;
    const int l = threadIdx.x & 63;
    const int wid = threadIdx.x >> 6;
    const unsigned wave = blockIdx.x * 4u + (unsigned)wid;
    const unsigned nwave = gridDim.x * 4u;
    for (unsigned i = wave; i < nf; i += nwave) {
        const int row = (int)flaglist[i];
        ((float*)xls4[wid])[l] = in[(size_t)l * NR + row];  // wave-local
        double best = 1e300; int bestk = 0;
        for (int ci = 0; ci < 16; ++ci) {
            const int k = ci * 64 + l;              // ascending k per lane
            double s0 = 0.0, s1 = 0.0, e0 = 0.0, e1 = 0.0;
#pragma unroll
            for (int e4 = 0; e4 < 16; e4 += 2) {
                const float4 ca = cbT4[(size_t)e4 * KC + k];       // coalesced
                const float4 cbv = cbT4[(size_t)(e4 + 1) * KC + k];
                const float4 xa = xls4[wid][e4];                   // broadcast
                const float4 xb = xls4[wid][e4 + 1];
                e0 = fma((double)ca.x, (double)ca.x, e0);
                s0 = fma((double)ca.x, (double)xa.x, s0);
                e1 = fma((double)cbv.x, (double)cbv.x, e1);
                s1 = fma((double)cbv.x, (double)xb.x, s1);
                e0 = fma((double)ca.y, (double)ca.y, e0);
                s0 = fma((double)ca.y, (double)xa.y, s0);
                e1 = fma((double)cbv.y, (double)cbv.y, e1);
                s1 = fma((double)cbv.y, (double)xb.y, s1);
                e0 = fma((double)ca.z, (double)ca.z, e0);
                s0 = fma((double)ca.z, (double)xa.z, s0);
                e1 = fma((double)cbv.z, (double)cbv.z, e1);
                s1 = fma((double)cbv.z, (double)xb.z, s1);
                e0 = fma((double)ca.w, (double)ca.w, e0);
                s0 = fma((double)ca.w, (double)xa.w, s0);
                e1 = fma((double)cbv.w, (double)cbv.w, e1);
                s1 = fma((double)cbv.w, (double)xb.w, s1);
            }
            const double t = fma(-2.0, s0 + s1, e0 + e1);
            if (t < best) { best = t; bestk = k; }
        }
        for (int sh = 1; sh < 64; sh <<= 1) {
            const double ob = __shfl_xor(best, sh, 64);
            const int   ok  = __shfl_xor(bestk, sh, 64);
            if (ob < best || (ob == best && ok < bestk)) { best = ob; bestk = ok; }
        }
        const int old = idx[row];                  // same addr all lanes
        if (bestk != old) {
            if (l == 0) {
                idx[row] = bestk;
                atomicSub(&counts[old], 1u);
                atomicAdd(&counts[bestk], 1u);
            }
            qout[(size_t)l * NR + row] = cb[(size_t)bestk * ED + l];
        }
    }

    // Done-ticket: last block computes the two scalars.
    __shared__ unsigned isLast;
    __threadfence();
    __syncthreads();
    if (threadIdx.x == 0) isLast = (atomicAdd(done, 1u) == gridDim.x - 1u);
    __syncthreads();
    if (isLast) {
        __threadfence();                           // see all blocks' writes
        __shared__ double redE[4], redS[4];
        const int tid = threadIdx.x;
        double term = 0.0;
#pragma unroll
        for (int i = 0; i < 4; ++i) {
            const double p = (double)counts[tid + i * 256] * (1.0 / 65536.0);
            term += p * log(p + 1e-10);
        }
        double s = 0.0;
#pragma unroll
        for (int i = 0; i < 8; ++i) s += pblk[tid + i * 256];
#pragma unroll
        for (int off = 32; off > 0; off >>= 1) {
            term += __shfl_down(term, off, 64);
            s    += __shfl_down(s,    off, 64);
        }
        if ((tid & 63) == 0) { redE[tid >> 6] = term; redS[tid >> 6] = s; }
        __syncthreads();
        if (tid == 0) {
            const double e = (redE[0] + redE[1]) + (redE[2] + redE[3]);
            const double ss = (redS[0] + redS[1]) + (redS[2] + redS[3]);
            out[1 + NE] = (float)exp(-e);             // perplexity
            const double m = ss * (1.0 / 4194304.0);  // mean((q-x)^2)
            out[0] = (float)(1.25 * m);               // (1+beta)*m
        }
    }
}

extern "C" void kernel_launch(void* const* d_in, const int* in_sizes, int n_in,
                              void* d_out, int out_size, void* d_ws, size_t ws_size,
                              hipStream_t stream) {
    (void)in_sizes; (void)n_in; (void)out_size; (void)ws_size;
    const float* in = (const float*)d_in[0];
    const float* cb = (const float*)d_in[1];
    float* out = (float*)d_out;

    // ws layout (dword offsets), strictly disjoint -- audited end-to-end:
    //  [0,1024) counts | [1024] flagcnt | [1025] done
    //  [2048,83968)    cbt: 64 tiles x 320 short8 x 4 dw = 81920 dw (320KB)
    //  [83968,149504)  idx (65536)
    //  [149504,215040) flaglist (65536)
    //  [215040,219136) pblk: 2048 f64 (byte 860160, 8B-aligned)
    //  [219136,284672) cbT4: 16384 float4 (byte 876544, 16B-aligned)
    unsigned* counts   = (unsigned*)d_ws;
    unsigned* flagcnt  = (unsigned*)d_ws + 1024;
    unsigned* done     = (unsigned*)d_ws + 1025;
    short8*   cbt      = (short8*)((float*)d_ws + 2048);
    int*      idx      = (int*)d_ws + 83968;
    unsigned* flaglist = (unsigned*)d_ws + 149504;
    double*   pblk     = (double*)((char*)d_ws + 860160);
    float4*   cbT4     = (float4*)((float*)d_ws + 219136);

    hipLaunchKernelGGL(k_pack,    dim3(80),   dim3(256), 0, stream,
                       cb, cbt, cbT4, counts, flagcnt, done);
    hipLaunchKernelGGL(k_argmin,  dim3(2048), dim3(256), 0, stream,
                       in, cbt, cb, idx, out + 1, counts, flagcnt, flaglist, pblk);
    hipLaunchKernelGGL(k_exact64, dim3(1024), dim3(256), 0, stream,
                       in, cb, cbT4, idx, out + 1, counts, flagcnt, flaglist,
                       done, pblk, out);
}

// Round 28
// 83.750 us; speedup vs baseline: 1.7821x; 1.7821x over previous
//
#include <hip/hip_runtime.h>

// VQ-VAE VectorQuantizer fwd. K=1024, E=64, N=T*B=65536.
// 2-tier argmin: 3-term bf16-split MFMA (GAP1=6e-6, flags ~350) -> fp64
// exact re-resolve.
// R28: UN-FUSE the final scalars. R25-R27's done-ticket put a device-scope
// __threadfence() in every exact64 block; fences serialize L2 drains:
// identical scan body cost 12us plain (R24), 56us with ticket at 128 blk
// (R25), 116us at 1024 blk (R27). Reverted to separate 1-block k_final.
// k_argmin = R25's 32-row/wave version (xq 32 VGPR resident, ~25us).
// k_exact64 = R24's plain body (x in regs, one wave/row), 256 blocks.
// Scores t = ||c||^2 - 2 x.c; codebook pre-scaled by -2, ||c||^2 in C-init.
// MFMA: A = codebook frag, B = x frag -> D(lane l, reg r) =
// score(code = t*16 + (l>>4)*4 + r, row = base + (l&15)).

#define KC 1024
#define ED 64
#define NR 65536
#define NE (NR * ED)
#define GAP1 6e-6f

typedef __attribute__((ext_vector_type(8))) short short8;
typedef __attribute__((ext_vector_type(4))) float f32x4;

__device__ __forceinline__ unsigned short bf16rne(float f) {
    unsigned u = __builtin_bit_cast(unsigned, f);
    return (unsigned short)((u + 0x7fffu + ((u >> 16) & 1u)) >> 16);
}
__device__ __forceinline__ float bf16tof(unsigned short h) {
    return __builtin_bit_cast(float, (unsigned)h << 16);
}

// Pack compact tile records (stride 320 short8 = 5KB) + zero counters.
// Record t: j=0,1 = ch (hi bf16 of -2*c) for e in [0,32),[32,64); j=2,3 =
// cl (lo residual); elem (g=l>>4,r) <-> e = (j&1)*32 + g*8 + r (same
// bijection as the x fragments); j=4: f32x4 ||c||^2 (reg r <-> code
// t*16+(l>>4)*4+r) bitcast short8.
__global__ __launch_bounds__(256) void k_pack(const float* __restrict__ cb,
        short8* __restrict__ cbt, unsigned* __restrict__ counts,
        unsigned* __restrict__ flagcnt) {
    const int u = blockIdx.x * 256 + threadIdx.x;
    if (u < 1024) counts[u] = 0u;
    if (u == 1024) *flagcnt = 0u;
    if (u >= 64 * 5 * 64) return;
    const int t = u / 320, rem = u % 320, j = rem / 64, l = rem % 64;
    const int g = l >> 4;
    if (j < 4) {
        const int code = t * 16 + (l & 15);
        const float* c = cb + (size_t)code * ED;
        const bool lo = (j >= 2);
        short8 o;
#pragma unroll
        for (int r = 0; r < 8; ++r) {
            const int e = (j & 1) * 32 + g * 8 + r;
            const float m2 = -2.f * c[e];
            const unsigned short h = bf16rne(m2);
            o[r] = lo ? (short)bf16rne(m2 - bf16tof(h)) : (short)h;
        }
        cbt[u] = o;
    } else {
        f32x4 o;
#pragma unroll
        for (int r = 0; r < 4; ++r) {
            const float4* c4 = (const float4*)(cb + (size_t)(t * 16 + g * 4 + r) * ED);
            float s0 = 0.f, s1 = 0.f, s2 = 0.f, s3 = 0.f;
#pragma unroll
            for (int i = 0; i < 16; ++i) {
                const float4 c = c4[i];
                s0 = fmaf(c.x, c.x, s0); s1 = fmaf(c.y, c.y, s1);
                s2 = fmaf(c.z, c.z, s2); s3 = fmaf(c.w, c.w, s3);
            }
            o[r] = (s0 + s1) + (s2 + s3);
        }
        cbt[u] = __builtin_bit_cast(short8, o);
    }
}

// 2048 blocks x 256 thr (4 waves = 4 K-quarters), 32 rows/block, 8
// blocks/CU. Phase 1: cooperative x -> bf16 hi/lo frags into LDS +
// ||x||^2 partials. Phase 2: wave kh holds its 8 x-frags in 32 VGPR
// (resident), scans tiles [kh*16,+16): 5 loads + 12 MFMA + min-track.
// Phase 3: shfl g-merge; wave 0 (lanes<32) merges kh slices (ascending k
// tie-break), writes idx/fidx/histogram/flag/SSE. Phase 4: qout gather.
__global__ __launch_bounds__(256) void k_argmin(
        const float* __restrict__ in, const short8* __restrict__ cbt,
        const float* __restrict__ cb, int* __restrict__ idx,
        float* __restrict__ qout, unsigned* __restrict__ counts,
        unsigned* __restrict__ flagcnt, unsigned* __restrict__ flaglist,
        double* __restrict__ pblk) {
    __shared__ short8 xs[8][64];                  // 8 KB
    __shared__ float rx2p[8][32];                 // 1 KB
    __shared__ float sb[4][2][16], sb2[4][2][16];
    __shared__ int   sk[4][2][16];                // 1.5 KB
    __shared__ int   fidx[32];

    const int tid = threadIdx.x;
    const int l = tid & 63;
    const int wid = tid >> 6;                     // 0..3 == kh
    const int g = l >> 4;
    const int col = l & 15;
    const int rowBase = blockIdx.x * 32;

    // Phase 1: thread (row=tid&31, ob=tid>>5) converts its row's oct ob
    // (e = ob*8+j; hh=ob>>2, gg=ob&3); ll = gg*16+(row&15),
    // slot = (row>>4)*4 + hh (+2 for lo).
    {
        const int row = tid & 31;
        const int ob = tid >> 5;                  // 0..7
        const int hh = ob >> 2, gg = ob & 3;
        const int rt = row >> 4;
        const int ll = gg * 16 + (row & 15);
        float part = 0.f;
        short8 H, L;
#pragma unroll
        for (int j = 0; j < 8; ++j) {
            const float x = in[(size_t)(ob * 8 + j) * NR + rowBase + row];
            const unsigned short hb = bf16rne(x);
            H[j] = (short)hb;
            L[j] = (short)bf16rne(x - bf16tof(hb));
            part = fmaf(x, x, part);
        }
        xs[rt * 4 + hh][ll] = H;
        xs[rt * 4 + 2 + hh][ll] = L;
        rx2p[ob][row] = part;
    }
    __syncthreads();

    // Phase 2: 8 x-frags to regs (32 VGPR, resident), simple tile loop.
    const int kh = wid;
    short8 xq[2][4];
#pragma unroll
    for (int rt = 0; rt < 2; ++rt)
#pragma unroll
        for (int q = 0; q < 4; ++q)
            xq[rt][q] = xs[rt * 4 + q][l];

    float best[2]  = {3.4e38f, 3.4e38f};
    float best2[2] = {3.4e38f, 3.4e38f};
    int bestk[2] = {0, 0};

#pragma unroll 2
    for (int tt = 0; tt < 16; ++tt) {
        const int t = kh * 16 + tt;
        const short8* bp = cbt + (size_t)t * 320 + l;
        const short8 b0 = bp[0], b1 = bp[64], b2 = bp[128], b3 = bp[192];
        const f32x4 e4 = __builtin_bit_cast(f32x4, bp[256]);
#pragma unroll
        for (int rt = 0; rt < 2; ++rt) {
            f32x4 acc = e4;
            acc = __builtin_amdgcn_mfma_f32_16x16x32_bf16(b0, xq[rt][0], acc, 0, 0, 0);
            acc = __builtin_amdgcn_mfma_f32_16x16x32_bf16(b1, xq[rt][1], acc, 0, 0, 0);
            acc = __builtin_amdgcn_mfma_f32_16x16x32_bf16(b2, xq[rt][0], acc, 0, 0, 0);
            acc = __builtin_amdgcn_mfma_f32_16x16x32_bf16(b3, xq[rt][1], acc, 0, 0, 0);
            acc = __builtin_amdgcn_mfma_f32_16x16x32_bf16(b0, xq[rt][2], acc, 0, 0, 0);
            acc = __builtin_amdgcn_mfma_f32_16x16x32_bf16(b1, xq[rt][3], acc, 0, 0, 0);
#pragma unroll
            for (int r = 0; r < 4; ++r) {
                const float v = acc[r];
                const int k = t * 16 + g * 4 + r;
                best2[rt] = fminf(fmaxf(v, best[rt]), best2[rt]);  // med3
                const bool c = v < best[rt];
                bestk[rt] = c ? k : bestk[rt];
                best[rt]  = fminf(v, best[rt]);
            }
        }
    }

    // Phase 3a: intra-wave g-merge; g==0 writes per-kh partials.
#pragma unroll
    for (int rt = 0; rt < 2; ++rt) {
        float b = best[rt], b2 = best2[rt]; int k = bestk[rt];
#pragma unroll
        for (int sh = 16; sh <= 32; sh <<= 1) {
            const float ob  = __shfl_xor(b, sh, 64);
            const float ob2 = __shfl_xor(b2, sh, 64);
            const int   ok  = __shfl_xor(k, sh, 64);
            if (ob < b || (ob == b && ok < k)) { b2 = fminf(b, ob2); k = ok; b = ob; }
            else b2 = fminf(b2, ob);
        }
        if (g == 0) { sb[wid][rt][col] = b; sb2[wid][rt][col] = b2; sk[wid][rt][col] = k; }
    }
    __syncthreads();

    // Phase 3b: wave 0, lanes < 32: lane l owns row ((l>>4)&1)*16 + (l&15).
    if (wid == 0) {
        const int rt = (l >> 4) & 1, c2 = l & 15;
        const bool act = (l < 32);
        float b = sb[0][rt][c2], b2 = sb2[0][rt][c2]; int k = sk[0][rt][c2];
#pragma unroll
        for (int s = 1; s < 4; ++s) {              // ascending k ranges
            const float ob = sb[s][rt][c2], ob2 = sb2[s][rt][c2];
            const int ok = sk[s][rt][c2];
            if (ob < b || (ob == b && ok < k)) { b2 = fminf(b, ob2); k = ok; b = ob; }
            else b2 = fminf(b2, ob);
        }
        const int lrow = rt * 16 + c2;
        const int row = rowBase + lrow;
        double d2 = 0.0;
        if (act) {
            idx[row] = k;
            fidx[lrow] = k;
            atomicAdd(&counts[k], 1u);
            if (b2 - b < GAP1) {
                const unsigned p = atomicAdd(flagcnt, 1u);
                flaglist[p] = (unsigned)row;
            }
            float rx = 0.f;
#pragma unroll
            for (int o = 0; o < 8; ++o) rx += rx2p[o][lrow];
            d2 = (double)b + (double)rx;
        }
#pragma unroll
        for (int off = 16; off > 0; off >>= 1) d2 += __shfl_down(d2, off, 64);
        if (l == 0) pblk[blockIdx.x] = d2;
    }
    __syncthreads();

    // Phase 4: cooperative gather; thread (row=tid&31, e0=tid>>5).
    {
        const int row = tid & 31;
        const int e0 = tid >> 5;                  // 0..7
        const int k = fidx[row];
        const float4* c4 = (const float4*)(cb + (size_t)k * ED + e0 * 8);
        const float4 v0 = c4[0], v1 = c4[1];
        qout[(size_t)(e0 * 8 + 0) * NR + rowBase + row] = v0.x;
        qout[(size_t)(e0 * 8 + 1) * NR + rowBase + row] = v0.y;
        qout[(size_t)(e0 * 8 + 2) * NR + rowBase + row] = v0.z;
        qout[(size_t)(e0 * 8 + 3) * NR + rowBase + row] = v0.w;
        qout[(size_t)(e0 * 8 + 4) * NR + rowBase + row] = v1.x;
        qout[(size_t)(e0 * 8 + 5) * NR + rowBase + row] = v1.y;
        qout[(size_t)(e0 * 8 + 6) * NR + rowBase + row] = v1.z;
        qout[(size_t)(e0 * 8 + 7) * NR + rowBase + row] = v1.w;
    }
}

// fp64 exact argmin for flagged rows (~350); one wave per row; adjusts
// histogram and rewrites the row's qout column on change. Plain kernel:
// NO fence, NO ticket (R25-R27's fused fence cost 44-100us).
__global__ __launch_bounds__(256) void k_exact64(
        const float* __restrict__ in, const float* __restrict__ cb,
        int* __restrict__ idx, float* __restrict__ qout,
        unsigned* __restrict__ counts,
        const unsigned* __restrict__ flagcnt, const unsigned* __restrict__ flaglist) {
    const unsigned nf = *flagcnt;
    const int l = threadIdx.x & 63;
    const unsigned wave = blockIdx.x * 4u + (unsigned)(threadIdx.x >> 6);
    const unsigned nwave = gridDim.x * 4u;
    for (unsigned i = wave; i < nf; i += nwave) {
        const int row = (int)flaglist[i];
        float x[ED];
#pragma unroll
        for (int e = 0; e < ED; ++e) x[e] = in[(size_t)e * NR + row];
        double best = 1e300; int bestk = 0;
        for (int ci = 0; ci < 16; ++ci) {
            const int k = ci * 64 + l;              // ascending k per lane
            const float* c = cb + (size_t)k * ED;
            double s = 0.0, e2 = 0.0;
            for (int e = 0; e < ED; ++e) {
                const double cv = (double)c[e];
                e2 = fma(cv, cv, e2);
                s  = fma(cv, (double)x[e], s);
            }
            const double t = fma(-2.0, s, e2);
            if (t < best) { best = t; bestk = k; }
        }
        for (int sh = 1; sh < 64; sh <<= 1) {
            const double ob = __shfl_xor(best, sh, 64);
            const int   ok  = __shfl_xor(bestk, sh, 64);
            if (ob < best || (ob == best && ok < bestk)) { best = ob; bestk = ok; }
        }
        const int old = idx[row];                  // same addr all lanes
        if (bestk != old) {
            if (l == 0) {
                idx[row] = bestk;
                atomicSub(&counts[old], 1u);
                atomicAdd(&counts[bestk], 1u);
            }
            qout[(size_t)l * NR + row] = cb[(size_t)bestk * ED + l];
        }
    }
}

// Scalars: entropy from final counts + SSE from 2048 per-block partials
// (fixed-order tree -> deterministic).
__global__ __launch_bounds__(1024) void k_final(const unsigned* __restrict__ counts,
        const double* __restrict__ pblk, float* __restrict__ out) {
    __shared__ double redE[16], redS[16];
    const int tid = threadIdx.x;
    const double p = (double)counts[tid] * (1.0 / 65536.0);
    double term = p * log(p + 1e-10);
    double s = pblk[tid] + pblk[tid + 1024];
#pragma unroll
    for (int off = 32; off > 0; off >>= 1) {
        term += __shfl_down(term, off, 64);
        s    += __shfl_down(s,    off, 64);
    }
    if ((tid & 63) == 0) { redE[tid >> 6] = term; redS[tid >> 6] = s; }
    __syncthreads();
    if (tid == 0) {
        double e = 0.0, ss = 0.0;
        for (int i = 0; i < 16; ++i) { e += redE[i]; ss += redS[i]; }
        out[1 + NE] = (float)exp(-e);                 // perplexity
        const double m = ss * (1.0 / 4194304.0);      // mean((q-x)^2)
        out[0] = (float)(1.25 * m);                   // (1+beta)*m
    }
}

extern "C" void kernel_launch(void* const* d_in, const int* in_sizes, int n_in,
                              void* d_out, int out_size, void* d_ws, size_t ws_size,
                              hipStream_t stream) {
    (void)in_sizes; (void)n_in; (void)out_size; (void)ws_size;
    const float* in = (const float*)d_in[0];
    const float* cb = (const float*)d_in[1];
    float* out = (float*)d_out;

    // ws layout (dword offsets), strictly disjoint -- audited end-to-end:
    //  [0,1024) counts | [1024] flagcnt
    //  [2048,83968)    cbt: 64 tiles x 320 short8 x 4 dw = 81920 dw (320KB)
    //  [83968,149504)  idx (65536)
    //  [149504,215040) flaglist (65536)
    //  [215040,219136) pblk: 2048 f64 (byte 860160, 8B-aligned)
    unsigned* counts   = (unsigned*)d_ws;
    unsigned* flagcnt  = (unsigned*)d_ws + 1024;
    short8*   cbt      = (short8*)((float*)d_ws + 2048);
    int*      idx      = (int*)d_ws + 83968;
    unsigned* flaglist = (unsigned*)d_ws + 149504;
    double*   pblk     = (double*)((char*)d_ws + 860160);

    hipLaunchKernelGGL(k_pack,    dim3(80),   dim3(256),  0, stream,
                       cb, cbt, counts, flagcnt);
    hipLaunchKernelGGL(k_argmin,  dim3(2048), dim3(256),  0, stream,
                       in, cbt, cb, idx, out + 1, counts, flagcnt, flaglist, pblk);
    hipLaunchKernelGGL(k_exact64, dim3(256),  dim3(256),  0, stream,
                       in, cb, idx, out + 1, counts, flagcnt, flaglist);
    hipLaunchKernelGGL(k_final,   dim3(1),    dim3(1024), 0, stream,
                       counts, pblk, out);
}